// Round 6
// baseline (171.563 us; speedup 1.0000x reference)
//
#include <hip/hip_runtime.h>
#include <math.h>

// CAP = (300+400+900)/300/1000*300400 = 1602.13333...; thresh = 0.2*CAP
#define THRESH 320.42666666666668f
#define NBLOCKS 768          // 3 blocks/CU (48KB LDS each) -> 12 waves/CU
#define CH_DAYS 32           // days per chunk: 32*96*4B = 12KB per array
#define CH_FLOATS (CH_DAYS * 96)   // 3072
#define DEPTH 2              // double-buffered chunk pipeline, 1 chunk ahead

typedef const __attribute__((address_space(1))) void* gas_t;  // global
typedef __attribute__((address_space(3))) void*       las_t;  // LDS

// accumulate 4 elements' squared relative error into s
#define ACC4(tv, pv)                                                                \
    do {                                                                            \
        float r;                                                                    \
        r = (tv.x - pv.x) * __builtin_amdgcn_rcpf(fmaxf(tv.x, THRESH)); s += r * r; \
        r = (tv.y - pv.y) * __builtin_amdgcn_rcpf(fmaxf(tv.y, THRESH)); s += r * r; \
        r = (tv.z - pv.z) * __builtin_amdgcn_rcpf(fmaxf(tv.z, THRESH)); s += r * r; \
        r = (tv.w - pv.w) * __builtin_amdgcn_rcpf(fmaxf(tv.w, THRESH)); s += r * r; \
    } while (0)

// Wave w DMA-stages ITS OWN 8-day quarter of a chunk (bytes [w*3072, w*3072+3072)
// per array) -> no cross-wave LDS dependency -> no barriers, per-wave vmcnt only.
// 6 global_load_lds_dwordx4 per wave per chunk (3 per array).  [proven in r3]
__device__ __forceinline__ void stage_chunk(
    const float* __restrict__ tru, const float* __restrict__ pred,
    float* lds_t, float* lds_p, long day0, int w, int lane)
{
    const size_t base = (size_t)day0 * 96 + (size_t)w * 768;
#pragma unroll
    for (int i = 0; i < 3; ++i) {
        const float* gt = tru  + base + i * 256 + lane * 4;
        const float* gp = pred + base + i * 256 + lane * 4;
        // LDS dest is wave-uniform; lane writes dest + lane*16 (matches source).
        __builtin_amdgcn_global_load_lds((gas_t)(const void*)gt,
                                         (las_t)(void*)(lds_t + w * 768 + i * 256), 16, 0, 0);
        __builtin_amdgcn_global_load_lds((gas_t)(const void*)gp,
                                         (las_t)(void*)(lds_p + w * 768 + i * 256), 16, 0, 0);
    }
}

// Wave w scores its 8 staged days: 8 lanes/day, 12 floats/lane (3 ds_read_b128
// pairs). Bank check: dword addr = dl*96 + k*12 -> the 8 k-slots start at banks
// {0,12,24,4,16,28,8,20}, each b128 spans 4 banks -> exact 32-bank tiling,
// minimum 8-way aliasing for 256 bank-accesses (free).  [proven in r3]
__device__ __forceinline__ float chunk_score(
    const float* lds_t, const float* lds_p, int w, int lane)
{
    const int dl = w * 8 + (lane >> 3);  // day within chunk
    const int k  = lane & 7;             // 12-float slice within day
    const float4* t4 = (const float4*)(lds_t + dl * 96 + k * 12);
    const float4* p4 = (const float4*)(lds_p + dl * 96 + k * 12);
    float s = 0.0f;
#pragma unroll
    for (int j = 0; j < 3; ++j) {
        const float4 tv = t4[j];
        const float4 pv = p4[j];
        ACC4(tv, pv);
    }
    // fold the 8 k-slices (lane bits 0..2); all 8 lanes of a day get the total
    s += __shfl_xor(s, 1);
    s += __shfl_xor(s, 2);
    s += __shfl_xor(s, 4);
    return (1.0f - sqrtf(s * (1.0f / 96.0f))) * 100.0f;
}

__global__ __launch_bounds__(256) void day_score_kernel(
    const float* __restrict__ pred, const float* __restrict__ tru,
    float* __restrict__ out, int num_days, float scale)
{
    __shared__ float lds[DEPTH][2][CH_FLOATS];   // 48 KB: 3 blocks/CU
    __shared__ float wsum[4];
    const int tid  = threadIdx.x;
    const int w    = tid >> 6;
    const int lane = tid & 63;
    const int b    = (int)blockIdx.x;
    const int nchunks = num_days / CH_DAYS;      // 6250 at 200000 days

    // grid-stride over chunks: cid = b + j*NBLOCKS (8 or 9 chunks per block)
    const int nmine = (nchunks > b) ? (nchunks - b + NBLOCKS - 1) / NBLOCKS : 0;

    // prologue: fill the pipeline (DEPTH chunks in flight, 12 DMA instrs/wave)
    for (int j = 0; j < DEPTH && j < nmine; ++j) {
        const long day0 = (long)(b + j * NBLOCKS) * CH_DAYS;
        stage_chunk(tru, pred, lds[j][0], lds[j][1], day0, w, lane);
    }

    float acc = 0.0f;
    for (int j = 0; j < nmine; ++j) {
        const int ahead = nmine - 1 - j;   // chunks issued beyond j (block-uniform)
        // counted wait: chunk j's 6 DMAs done, newer chunk stays in flight (T4)
        if (ahead >= 1) { asm volatile("s_waitcnt vmcnt(6)" ::: "memory"); }
        else            { asm volatile("s_waitcnt vmcnt(0)" ::: "memory"); }
        __builtin_amdgcn_sched_barrier(0);

        const int slot = j & 1;
        acc += chunk_score(lds[slot][0], lds[slot][1], w, lane);

        asm volatile("" ::: "memory");     // keep ds_reads above the slot refill
        if (j + DEPTH < nmine) {
            const long day0 = (long)(b + (j + DEPTH) * NBLOCKS) * CH_DAYS;
            stage_chunk(tru, pred, lds[slot][0], lds[slot][1], day0, w, lane);
        }
    }

    // tail days (num_days % 32; zero at 200000) — scalar on one lane, after all
    // DMA drained so compiler waitcnt bookkeeping is exact again.
    if (b == 0 && tid == 0) {
        for (int day = nchunks * CH_DAYS; day < num_days; ++day) {
            const float* t = tru  + (size_t)day * 96;
            const float* p = pred + (size_t)day * 96;
            float s = 0.0f;
            for (int j = 0; j < 96; ++j) {
                const float d = (t[j] - p[j]) / fmaxf(t[j], THRESH);
                s += d * d;
            }
            acc += (1.0f - sqrtf(s * (1.0f / 96.0f))) * 100.0f;
        }
    }

    // fold the 8 day-groups (lane bits 3..5); bits 0..2 already folded per chunk,
    // so each day is counted exactly ONCE in lane 0's total.
    acc += __shfl_xor(acc, 8);
    acc += __shfl_xor(acc, 16);
    acc += __shfl_xor(acc, 32);
    if (lane == 0) wsum[w] = acc;
    __syncthreads();
    if (tid == 0) {
        const float blk = (wsum[0] + wsum[1]) + (wsum[2] + wsum[3]);
        atomicAdd(out, blk * scale);         // proven path (r0-r2), no workspace
    }
}

extern "C" void kernel_launch(void* const* d_in, const int* in_sizes, int n_in,
                              void* d_out, int out_size, void* d_ws, size_t ws_size,
                              hipStream_t stream) {
    (void)n_in; (void)d_ws; (void)ws_size;
    const float* pred = (const float*)d_in[0];   // setup_inputs: {"pred": ..., "true": ...}
    const float* tru  = (const float*)d_in[1];
    float* out = (float*)d_out;

    const int n        = in_sizes[1];
    const int num_days = n / 96;
    const float scale  = 1.0f / (float)num_days;

    hipMemsetAsync(out, 0, (size_t)out_size * sizeof(float), stream);
    day_score_kernel<<<NBLOCKS, 256, 0, stream>>>(pred, tru, out, num_days, scale);
}

// Round 9
// 170.972 us; speedup vs baseline: 1.0035x; 1.0035x over previous
//
#include <hip/hip_runtime.h>
#include <math.h>

// CAP = (300+400+900)/300/1000*300400 = 1602.13333...; thresh = 0.2*CAP
#define THRESH 320.42666666666668f
#define NBLOCKS 768
#define UNIT_FLOATS 768        // 8-day unit: 8*96 floats = 3 KB per array
#define A_WAVES 2048           // path-A waves: 512 blocks x 4
#define B_WAVES 1024           // path-B waves: 256 blocks x 4

typedef const __attribute__((address_space(1))) void* gas_t;  // global
typedef __attribute__((address_space(3))) void*       las_t;  // LDS

// accumulate 4 elements' squared relative error into s
#define ACC4(tv, pv)                                                                \
    do {                                                                            \
        float r;                                                                    \
        r = (tv.x - pv.x) * __builtin_amdgcn_rcpf(fmaxf(tv.x, THRESH)); s += r * r; \
        r = (tv.y - pv.y) * __builtin_amdgcn_rcpf(fmaxf(tv.y, THRESH)); s += r * r; \
        r = (tv.z - pv.z) * __builtin_amdgcn_rcpf(fmaxf(tv.z, THRESH)); s += r * r; \
        r = (tv.w - pv.w) * __builtin_amdgcn_rcpf(fmaxf(tv.w, THRESH)); s += r * r; \
    } while (0)

// DMA-stage one 8-day unit (3KB per array) into this wave's private LDS slot.
// 6 global_load_lds_dwordx4 (1KB each); dest wave-uniform, lane adds lane*16B.
// [mechanism proven r3/r6]
__device__ __forceinline__ void stage_unit(
    const float* __restrict__ tru, const float* __restrict__ pred,
    float* dst_t, float* dst_p, long u, int lane)
{
    const size_t base = (size_t)u * UNIT_FLOATS;
#pragma unroll
    for (int i = 0; i < 3; ++i) {
        __builtin_amdgcn_global_load_lds((gas_t)(const void*)(tru  + base + i * 256 + lane * 4),
                                         (las_t)(void*)(dst_t + i * 256), 16, 0, 0);
        __builtin_amdgcn_global_load_lds((gas_t)(const void*)(pred + base + i * 256 + lane * 4),
                                         (las_t)(void*)(dst_p + i * 256), 16, 0, 0);
    }
}

// Score 8 staged days: 8 lanes/day (dl=lane>>3), 12 floats/lane (k=lane&7).
// Bank tiling: dword addr dl*96 + k*12 -> 8 k-slot starts {0,12,24,4,16,28,8,20}
// mod 32, b128 spans 4 banks -> exact 32-bank tiling (free). [proven r3/r6]
__device__ __forceinline__ float unit_score(
    const float* lt, const float* lp, int lane)
{
    const int dl = lane >> 3;
    const int k  = lane & 7;
    const float4* t4 = (const float4*)(lt + dl * 96 + k * 12);
    const float4* p4 = (const float4*)(lp + dl * 96 + k * 12);
    float s = 0.0f;
#pragma unroll
    for (int j = 0; j < 3; ++j) {
        const float4 tv = t4[j];
        const float4 pv = p4[j];
        ACC4(tv, pv);
    }
    // fold k-slices (lane bits 0..2): all 8 lanes of a day hold the day total
    s += __shfl_xor(s, 1);
    s += __shfl_xor(s, 2);
    s += __shfl_xor(s, 4);
    return (1.0f - sqrtf(s * (1.0f / 96.0f))) * 100.0f;
}

__global__ __launch_bounds__(256) void day_score_kernel(
    const float* __restrict__ pred, const float* __restrict__ tru,
    float* __restrict__ out, int num_days, float scale)
{
    // path-A per-wave private double buffer: [wave][slot][array][768] = 48 KB
    __shared__ float lds[4][2][2][UNIT_FLOATS];
    __shared__ float wsum[4];
    const int tid  = threadIdx.x;
    const int w    = tid >> 6;
    const int lane = tid & 63;
    const int b    = (int)blockIdx.x;

    const int nunits = num_days >> 3;        // 25000 at 200000 days
    const int half   = nunits >> 1;          // path A: units [0, half)
    float acc = 0.0f;

    // Block-level path split, parity on bit 8: blocks 0-255,512-767 -> A,
    // 256-511 -> B. With b mod 256 CU round-robin every CU hosts 2 A-blocks +
    // 1 B-block, so both read mechanisms run CONCURRENTLY on each CU (the A/B
    // probe target). All control flow below is block-uniform.
    if (((b >> 8) & 1) == 0) {
        // ---------- PATH A: global_load_lds DMA + counted vmcnt (r6 shape) ----
        const int aidx = (b >= 512) ? (b - 256) : b;   // 0..511
        const int gw   = aidx * 4 + w;                 // 0..2047
        int m = 0;
        if (gw < half) m = (half - gw + A_WAVES - 1) / A_WAVES;   // 6 or 7

        if (m > 0) stage_unit(tru, pred, lds[w][0][0], lds[w][0][1], (long)gw, lane);
        if (m > 1) stage_unit(tru, pred, lds[w][1][0], lds[w][1][1],
                              (long)gw + A_WAVES, lane);

        for (int k = 0; k < m; ++k) {
            if (k + 1 < m) { asm volatile("s_waitcnt vmcnt(6)" ::: "memory"); }
            else           { asm volatile("s_waitcnt vmcnt(0)" ::: "memory"); }
            __builtin_amdgcn_sched_barrier(0);

            const int s = k & 1;
            acc += unit_score(lds[w][s][0], lds[w][s][1], lane);

            asm volatile("" ::: "memory");   // keep ds_reads above the refill
            if (k + 2 < m)
                stage_unit(tru, pred, lds[w][s][0], lds[w][s][1],
                           (long)gw + (long)(k + 2) * A_WAVES, lane);
        }
    } else {
        // ---------- PATH B: plain float4 register loads (r2 shape) ------------
        const int gw = (b - 256) * 4 + w;              // 0..1023
        const int nd = nunits - half;                  // 12500
        int m = 0;
        if (gw < nd) m = (nd - gw + B_WAVES - 1) / B_WAVES;       // 12 or 13

        for (int k = 0; k < m; ++k) {
            const long u = (long)half + gw + (long)k * B_WAVES;
            // lane owns 12 contiguous floats = 3 float4 of its day-slice
            const float4* t4 = ((const float4*)tru)  + u * 192 + lane * 3;
            const float4* p4 = ((const float4*)pred) + u * 192 + lane * 3;
            const float4 t0 = t4[0], t1 = t4[1], t2 = t4[2];
            const float4 p0 = p4[0], p1 = p4[1], p2 = p4[2];
            float s = 0.0f;
            ACC4(t0, p0); ACC4(t1, p1); ACC4(t2, p2);
            s += __shfl_xor(s, 1);
            s += __shfl_xor(s, 2);
            s += __shfl_xor(s, 4);
            acc += (1.0f - sqrtf(s * (1.0f / 96.0f))) * 100.0f;
        }
    }

    // tail days (num_days % 8; zero at 200000) — scalar on one lane
    if (b == 0 && tid == 0) {
        for (int day = nunits * 8; day < num_days; ++day) {
            const float* t = tru  + (size_t)day * 96;
            const float* p = pred + (size_t)day * 96;
            float s = 0.0f;
            for (int j = 0; j < 96; ++j) {
                const float d = (t[j] - p[j]) / fmaxf(t[j], THRESH);
                s += d * d;
            }
            acc += (1.0f - sqrtf(s * (1.0f / 96.0f))) * 100.0f;
        }
    }

    // fold day-groups (lane bits 3..5): each day counted exactly once per lane;
    // identical semantics on both paths. [verified r6: absmax 0.0]
    acc += __shfl_xor(acc, 8);
    acc += __shfl_xor(acc, 16);
    acc += __shfl_xor(acc, 32);
    if (lane == 0) wsum[w] = acc;
    __syncthreads();
    if (tid == 0) {
        const float blk = (wsum[0] + wsum[1]) + (wsum[2] + wsum[3]);
        atomicAdd(out, blk * scale);         // proven path, no workspace
    }
}

extern "C" void kernel_launch(void* const* d_in, const int* in_sizes, int n_in,
                              void* d_out, int out_size, void* d_ws, size_t ws_size,
                              hipStream_t stream) {
    (void)n_in; (void)d_ws; (void)ws_size;
    const float* pred = (const float*)d_in[0];   // setup_inputs: {"pred": ..., "true": ...}
    const float* tru  = (const float*)d_in[1];
    float* out = (float*)d_out;

    const int n        = in_sizes[1];
    const int num_days = n / 96;
    const float scale  = 1.0f / (float)num_days;

    hipMemsetAsync(out, 0, (size_t)out_size * sizeof(float), stream);
    day_score_kernel<<<NBLOCKS, 256, 0, stream>>>(pred, tru, out, num_days, scale);
}